// Round 1
// baseline (47.945 us; speedup 1.0000x reference)
//
#include <hip/hip_runtime.h>

// 2D Gaussian splatting renderer, MI355X. R4.
// N=4096 gaussians, 512x512x3 fp32 image, 64 tiles of 64x64 px.
//
// R4 theory: render (~38us) was load-imbalance-bound, not VALU-bound
// (VALU floor ~8us). R3's co-resident blocks b, b+256 were the SAME tile
// ((b+256)&63 == b&63), so heavy tiles monopolized their SIMDs. Changes:
//  - per-tile list build hoisted to its own 64-block kernel that writes
//    contiguous pre-gathered {coeff,color} arrays per tile (kills 16x
//    redundant cull, makes render staging coalesced, removes s_list)
//  - render: 16-way X split per tile, 1 px/thread, 1024 blocks
//    -> 4 blocks/CU, 4 waves/SIMD; heavy tile spread over 64 waves
//  - scrambled tile map tile=(id+(id>>6))&63: co-resident blocks (stride
//    8 / 256 in dispatch order) always come from DIFFERENT tiles
//  - blend ALU: coeffs pre-scaled by log2e, log2(op) folded into the
//    exponent (alpha = exp2(q), no mul), v_med3 clamp. ~14 -> ~10 ops/px.

#define N_G    4096
#define W_IMG  512
#define TL_    64
#define NT_    8
#define NTILES 64
#define CHUNK  256
#define NSUB   16
#define LOG2E  1.44269504088896340736f

// ws layout (bytes):
//   [0,      65536) : float4 a4[N_G] = {px, py, qa, qb}   (depth-sorted)
//                     qa = -0.5*ia*log2e, qb = -0.5*ibc*log2e
//   [65536, 131072) : float4 b4[N_G] = {qc, lb, cr, cg}
//                     qc = -0.5*idd*log2e, lb = log2(op)
//   [131072,147456) : float  c1[N_G] = cb
//   [147456,163840) : float  rad[N_G]
//   [163840,164096) : int    cnt[64]
//   [0x100000, +4M) : float4 tA[64][4096]   per-tile gathered a4
//   [0x500000, +4M) : float4 tB[64][4096]   per-tile gathered b4
//   [0x900000, +1M) : float  tC[64][4096]   per-tile gathered c1

__global__ __launch_bounds__(256)
void gs_preprocess(const float* __restrict__ pos2d,
                   const float* __restrict__ cov2d,
                   const float* __restrict__ opacity,
                   const float* __restrict__ color,
                   float4* __restrict__ a4,
                   float4* __restrict__ b4,
                   float* __restrict__ c1,
                   float* __restrict__ rad_out) {
    __shared__ __align__(16) float s_depth[N_G];
    const int t = threadIdx.x;

    for (int k = t; k < N_G; k += 256)
        s_depth[k] = pos2d[k * 3 + 2];
    __syncthreads();

    const int g = t >> 4;                  // 16 gaussian slots per block
    const int s = t & 15;                  // 16-way j partition per gaussian
    const int i = blockIdx.x * 16 + g;     // 256 blocks x 16 = 4096
    const float di = s_depth[i];

    // j4 = s + 16k: 16 lanes hit 16 distinct 4-bank groups (free 2-way b128).
    const float4* s_d4 = (const float4*)s_depth;
    int rank = 0;
    #pragma unroll 8
    for (int k = 0; k < 64; ++k) {
        const int j4 = s + 16 * k;
        const float4 d = s_d4[j4];
        const int j = 4 * j4;
        rank += (d.x < di) || (d.x == di && (j + 0) < i);   // stable argsort
        rank += (d.y < di) || (d.y == di && (j + 1) < i);
        rank += (d.z < di) || (d.z == di && (j + 2) < i);
        rank += (d.w < di) || (d.w == di && (j + 3) < i);
    }
    rank += __shfl_xor(rank, 1);
    rank += __shfl_xor(rank, 2);
    rank += __shfl_xor(rank, 4);
    rank += __shfl_xor(rank, 8);

    if (s == 0) {
        const float px = pos2d[i * 3 + 0];
        const float py = pos2d[i * 3 + 1];
        const float a = cov2d[i * 4 + 0];
        const float b = cov2d[i * 4 + 1];
        const float c = cov2d[i * 4 + 2];
        const float d = cov2d[i * 4 + 3];

        const float trace = a + d;
        const float det = a * d - b * c;
        const float tmp = trace * trace - 4.0f * det;
        const float term2 = 0.5f * sqrtf(fmaxf(tmp, 0.0f));
        const float radius = 3.0f * sqrtf(fmaxf(0.5f * trace - term2, 0.5f * trace + term2));
        const float inv_det = 1.0f / det;
        const float ia  = d * inv_det;
        const float ibc = (-b * inv_det) + (-c * inv_det);  // match ref's ib+ic rounding
        const float idd = a * inv_det;

        const float op = opacity[i];
        const float cr = fmaxf(color[i * 3 + 0] + 0.5f, 0.0f);
        const float cg = fmaxf(color[i * 3 + 1] + 0.5f, 0.0f);
        const float cb = fmaxf(color[i * 3 + 2] + 0.5f, 0.0f);

        a4[rank] = make_float4(px, py, -0.5f * ia * LOG2E, -0.5f * ibc * LOG2E);
        b4[rank] = make_float4(-0.5f * idd * LOG2E, __log2f(op), cr, cg);
        c1[rank] = cb;
        rad_out[rank] = radius;
    }
}

// One block per tile: cull (cross-wave-stable, depth-ordered) + gather the
// listed gaussians' data into contiguous per-tile arrays.
__global__ __launch_bounds__(256)
void gs_tilelists(const float4* __restrict__ a4,
                  const float4* __restrict__ b4,
                  const float* __restrict__ c1,
                  const float* __restrict__ rad,
                  float4* __restrict__ tA,
                  float4* __restrict__ tB,
                  float* __restrict__ tC,
                  int* __restrict__ cnt) {
    __shared__ unsigned short s_list[N_G];
    __shared__ int s_wcnt[4];

    const int tile = blockIdx.x;
    const int tx = tile >> 3;
    const int ty = tile & 7;
    const float left = (float)(tx * TL_);
    const float top  = (float)(ty * TL_);
    const int t = threadIdx.x;
    const int wave = t >> 6;
    const int lane = t & 63;

    // 2-pass cross-wave-stable compaction; wave w owns [w*1024, (w+1)*1024)
    // so concatenated segments stay depth-ordered.
    unsigned int bits = 0;
    int wcnt = 0;
    #pragma unroll 4
    for (int it = 0; it < 16; ++it) {
        const int g = wave * 1024 + it * 64 + lane;
        const float4 A = a4[g];
        const float r = rad[g];
        const bool m = (A.x + r >= left) && (A.x - r < left + (float)TL_) &&
                       (A.y + r >= top)  && (A.y - r < top  + (float)TL_);
        bits |= (m ? 1u : 0u) << it;
        wcnt += __popcll(__ballot(m));
    }
    if (lane == 0) s_wcnt[wave] = wcnt;
    __syncthreads();
    const int c0 = s_wcnt[0], c1_ = s_wcnt[1], c2 = s_wcnt[2], c3 = s_wcnt[3];
    const int total = c0 + c1_ + c2 + c3;
    int base = (wave > 0 ? c0 : 0) + (wave > 1 ? c1_ : 0) + (wave > 2 ? c2 : 0);
    #pragma unroll 4
    for (int it = 0; it < 16; ++it) {
        const bool m = (bits >> it) & 1u;
        const unsigned long long bal = __ballot(m);
        const int prefix = __popcll(bal & ((1ULL << lane) - 1ULL));
        if (m) s_list[base + prefix] = (unsigned short)(wave * 1024 + it * 64 + lane);
        base += __popcll(bal);
    }
    __syncthreads();

    const int tb = tile << 12;              // tile * 4096
    for (int i = t; i < total; i += 256) {
        const int g = s_list[i];
        tA[tb + i] = a4[g];
        tB[tb + i] = b4[g];
        tC[tb + i] = c1[g];
    }
    if (t == 0) cnt[tile] = total;
}

__global__ __launch_bounds__(256, 4)
void gs_render(const float4* __restrict__ tA,
               const float4* __restrict__ tB,
               const float* __restrict__ tC,
               const int* __restrict__ cnt,
               float* __restrict__ out) {
    // 1024 blocks, 1 px/thread. tile scrambled so co-resident blocks
    // (dispatch strides 8 / 256) hit different tiles: tile=(id+(id>>6))&63.
    // Block covers 4 px in X, 64 in Y. Lane==Y -> coalesced stores.
    __shared__ __align__(16) float4 s_a[CHUNK];
    __shared__ __align__(16) float4 s_b[CHUNK];
    __shared__ float s_c[CHUNK];

    const int id = blockIdx.x;
    const int sub  = id >> 6;                  // 0..15
    const int tile = (id + sub) & 63;
    const int tx = tile >> 3;
    const int ty = tile & 7;
    const int t = threadIdx.x;

    const int X = tx * TL_ + sub * 4 + (t >> 6);
    const int Y = ty * TL_ + (t & 63);
    const float fX = (float)X;
    const float fY = (float)Y;

    const int total = cnt[tile];
    const int tb = tile << 12;

    float T = 1.f, R = 0.f, G = 0.f, B = 0.f;

    for (int cb_ = 0; cb_ < total; cb_ += CHUNK) {
        __syncthreads();   // protect s_a/s_b/s_c reuse
        const int gi = cb_ + t;
        if (gi < total) {
            s_a[t] = tA[tb + gi];
            s_b[t] = tB[tb + gi];
            s_c[t] = tC[tb + gi];
        }
        __syncthreads();

        const int n = min(CHUNK, total - cb_);
        #pragma unroll 4
        for (int k = 0; k < n; ++k) {
            const float4 A  = s_a[k];   // px, py, qa, qb
            const float4 Bv = s_b[k];   // qc, lb, cr, cg
            const float cbv = s_c[k];
            const float dy   = fY - A.y;
            const float qbdy = A.w * dy;
            const float bse  = Bv.x * dy * dy + Bv.y;       // qc*dy^2 + lb
            const float dx   = fX - A.x;
            const float q2   = (A.z * dx + qbdy) * dx + bse; // 2 fma
            const float e    = exp2f(q2);                    // e <= 1 always
            const float alpha = __builtin_amdgcn_fmed3f(e, 0.01f, 0.99f);
            const float w_ = alpha * T;
            R += w_ * Bv.z;
            G += w_ * Bv.w;
            B += w_ * cbv;
            T -= alpha * T;
        }
    }

    const int o = (X * W_IMG + Y) * 3;
    out[o + 0] = R;
    out[o + 1] = G;
    out[o + 2] = B;
}

extern "C" void kernel_launch(void* const* d_in, const int* in_sizes, int n_in,
                              void* d_out, int out_size, void* d_ws, size_t ws_size,
                              hipStream_t stream) {
    const float* pos2d   = (const float*)d_in[0];
    const float* cov2d   = (const float*)d_in[1];
    const float* opacity = (const float*)d_in[2];
    const float* color   = (const float*)d_in[3];
    float* out = (float*)d_out;

    char* ws = (char*)d_ws;
    float4* a4 = (float4*)(ws);
    float4* b4 = (float4*)(ws + 65536);
    float*  c1 = (float*)(ws + 131072);
    float*  rd = (float*)(ws + 147456);
    int*    ct = (int*)(ws + 163840);
    float4* tA = (float4*)(ws + 0x100000);
    float4* tB = (float4*)(ws + 0x500000);
    float*  tC = (float*)(ws + 0x900000);

    gs_preprocess<<<N_G / 16, 256, 0, stream>>>(pos2d, cov2d, opacity, color,
                                                a4, b4, c1, rd);
    gs_tilelists<<<NTILES, 256, 0, stream>>>(a4, b4, c1, rd, tA, tB, tC, ct);
    gs_render<<<NTILES * NSUB, 256, 0, stream>>>(tA, tB, tC, ct, out);
}

// Round 2
// 37.358 us; speedup vs baseline: 1.2834x; 1.2834x over previous
//
#include <hip/hip_runtime.h>

// 2D Gaussian splatting renderer, MI355X. R5.
// N=4096 gaussians, 512x512x3 fp32 image, 64 tiles of 64x64 px.
//
// R5 theory: dur_us = ~39us harness ws-poison fill (fixed floor, 256MiB at
// ~87% HBM peak) + our kernel chain. R3 chain ~4.3us; R4's 64-block
// tilelists kernel + 3rd launch DOUBLED the chain (~9us) - reverted.
// Changes vs R3:
//  - cull via precomputed per-gaussian 64-bit tile mask (preprocess builds
//    it; render cull = 8B load + bit test instead of 20B + 12 VALU)
//  - fixed co-residency scramble: tile=(id+(id>>6))&63 -> co-resident
//    blocks (b, b+256) land on tiles differing by 4 (R3: same tile)
//  - R4 blend kept: log2e-folded quadratic, log2(op) in exponent, one
//    exp2, v_med3 clamp (~23 VALU + 3 LDS per k-iter for 2 px)
//  - preprocess at 512 blocks (8 gaussians x 32-lane rank partitions):
//    2 waves/SIMD instead of 1 -> halves exposed-latency time

#define N_G    4096
#define W_IMG  512
#define TL_    64
#define NTILES 64
#define CHUNK  256
#define LOG2E  1.44269504088896340736f

// ws layout (bytes):
//   [0,      65536) : float4 a4[N_G] = {px, py, qa, qb}   (depth-sorted)
//                     qa = -0.5*ia*log2e, qb = -0.5*ibc*log2e
//   [65536, 131072) : float4 b4[N_G] = {qc, lb, cr, cg}
//                     qc = -0.5*idd*log2e, lb = log2(op)
//   [131072,147456) : float  c1[N_G]  = cb
//   [147456,180224) : u64    tmask[N_G] = tile-overlap bitmask (bit tx*8+ty)

__global__ __launch_bounds__(256)
void gs_preprocess(const float* __restrict__ pos2d,
                   const float* __restrict__ cov2d,
                   const float* __restrict__ opacity,
                   const float* __restrict__ color,
                   float4* __restrict__ a4,
                   float4* __restrict__ b4,
                   float* __restrict__ c1,
                   unsigned long long* __restrict__ tmask) {
    __shared__ __align__(16) float s_depth[N_G];
    const int t = threadIdx.x;

    for (int k = t; k < N_G; k += 256)
        s_depth[k] = pos2d[k * 3 + 2];
    __syncthreads();

    const int g = t >> 5;                  // 8 gaussian slots per block
    const int s = t & 31;                  // 32-way j partition per gaussian
    const int i = blockIdx.x * 8 + g;      // 512 blocks x 8 = 4096
    const float di = s_depth[i];

    // j4 = s + 32k: 32 lanes read 32 consecutive float4s (b128, conflict-free;
    // the two slots per wave read identical addresses -> broadcast, free).
    const float4* s_d4 = (const float4*)s_depth;
    int rank = 0;
    #pragma unroll 8
    for (int k = 0; k < 32; ++k) {
        const int j4 = s + 32 * k;
        const float4 d = s_d4[j4];
        const int j = 4 * j4;
        rank += (d.x < di) || (d.x == di && (j + 0) < i);   // stable argsort
        rank += (d.y < di) || (d.y == di && (j + 1) < i);
        rank += (d.z < di) || (d.z == di && (j + 2) < i);
        rank += (d.w < di) || (d.w == di && (j + 3) < i);
    }
    rank += __shfl_xor(rank, 1);
    rank += __shfl_xor(rank, 2);
    rank += __shfl_xor(rank, 4);
    rank += __shfl_xor(rank, 8);
    rank += __shfl_xor(rank, 16);

    if (s == 0) {
        const float px = pos2d[i * 3 + 0];
        const float py = pos2d[i * 3 + 1];
        const float a = cov2d[i * 4 + 0];
        const float b = cov2d[i * 4 + 1];
        const float c = cov2d[i * 4 + 2];
        const float d = cov2d[i * 4 + 3];

        const float trace = a + d;
        const float det = a * d - b * c;
        const float tmp = trace * trace - 4.0f * det;
        const float term2 = 0.5f * sqrtf(fmaxf(tmp, 0.0f));
        const float radius = 3.0f * sqrtf(fmaxf(0.5f * trace - term2, 0.5f * trace + term2));
        const float inv_det = 1.0f / det;
        const float ia  = d * inv_det;
        const float ibc = (-b * inv_det) + (-c * inv_det);  // match ref's ib+ic rounding
        const float idd = a * inv_det;

        const float op = opacity[i];
        const float cr = fmaxf(color[i * 3 + 0] + 0.5f, 0.0f);
        const float cg = fmaxf(color[i * 3 + 1] + 0.5f, 0.0f);
        const float cb = fmaxf(color[i * 3 + 2] + 0.5f, 0.0f);

        // Tile-overlap bitmask, bit (tx*8+ty); comparisons IDENTICAL to the
        // reference cull so the listed set matches exactly.
        unsigned int xm = 0, ym = 0;
        #pragma unroll
        for (int tc = 0; tc < 8; ++tc) {
            const float lo = (float)(tc * TL_);
            if ((px + radius >= lo) && (px - radius < lo + (float)TL_)) xm |= 1u << tc;
            if ((py + radius >= lo) && (py - radius < lo + (float)TL_)) ym |= 1u << tc;
        }
        unsigned long long m = 0ull;
        #pragma unroll
        for (int tc = 0; tc < 8; ++tc)
            if (xm & (1u << tc)) m |= (unsigned long long)ym << (8 * tc);

        a4[rank] = make_float4(px, py, -0.5f * ia * LOG2E, -0.5f * ibc * LOG2E);
        b4[rank] = make_float4(-0.5f * idd * LOG2E, __log2f(op), cr, cg);
        c1[rank] = cb;
        tmask[rank] = m;
    }
}

__global__ __launch_bounds__(256, 2)
void gs_render(const float4* __restrict__ a4,
               const float4* __restrict__ b4,
               const float* __restrict__ c1,
               const unsigned long long* __restrict__ tmask,
               float* __restrict__ out) {
    // 512 blocks, 2 px/thread. sub = id>>6 (0..7), tile = (id+sub)&63:
    // co-resident blocks (b, b+256) -> tiles differing by 4. Block covers
    // 8 px in X, 64 in Y. Lane==Y -> coalesced stores.
    __shared__ unsigned short s_list[N_G];
    __shared__ int s_wcnt[4];
    __shared__ __align__(16) float4 s_a[CHUNK];
    __shared__ __align__(16) float4 s_b[CHUNK];
    __shared__ float s_c[CHUNK];

    const int id = blockIdx.x;
    const int sub  = id >> 6;              // 0..7
    const int tile = (id + sub) & 63;
    const int tx = tile >> 3;
    const int ty = tile & 7;
    const int t = threadIdx.x;
    const int wave = t >> 6;
    const int lane = t & 63;

    // ---- cull via tile mask: 2-pass cross-wave-stable compaction, wave w
    //      owns g in [w*1024,(w+1)*1024) so concatenated segments stay
    //      depth-ordered.
    unsigned int bits = 0;
    int wcnt = 0;
    #pragma unroll 4
    for (int it = 0; it < 16; ++it) {
        const int g = wave * 1024 + it * 64 + lane;
        const bool m = (tmask[g] >> tile) & 1ull;
        bits |= (m ? 1u : 0u) << it;
        wcnt += __popcll(__ballot(m));
    }
    if (lane == 0) s_wcnt[wave] = wcnt;
    __syncthreads();
    const int c0 = s_wcnt[0], c1_ = s_wcnt[1], c2 = s_wcnt[2], c3 = s_wcnt[3];
    const int total = c0 + c1_ + c2 + c3;
    int base = (wave > 0 ? c0 : 0) + (wave > 1 ? c1_ : 0) + (wave > 2 ? c2 : 0);
    #pragma unroll 4
    for (int it = 0; it < 16; ++it) {
        const bool m = (bits >> it) & 1u;
        const unsigned long long bal = __ballot(m);
        const int prefix = __popcll(bal & ((1ULL << lane) - 1ULL));
        if (m) s_list[base + prefix] = (unsigned short)(wave * 1024 + it * 64 + lane);
        base += __popcll(bal);
    }
    // barrier before first s_list read is the chunk-loop-top __syncthreads

    const int X0 = tx * TL_ + sub * 8 + (t >> 6) * 2;
    const int Y  = ty * TL_ + (t & 63);
    const float fX = (float)X0;
    const float fY = (float)Y;

    float T0 = 1.f, T1 = 1.f;
    float R0 = 0.f, G0 = 0.f, B0 = 0.f;
    float R1 = 0.f, G1 = 0.f, B1 = 0.f;

    for (int cb_ = 0; cb_ < total; cb_ += CHUNK) {
        __syncthreads();   // protect s_list (1st iter) / s_a,s_b,s_c (reuse)
        const int gi = cb_ + t;
        if (gi < total) {
            const int g = s_list[gi];
            s_a[t] = a4[g];
            s_b[t] = b4[g];
            s_c[t] = c1[g];
        }
        __syncthreads();

        const int n = min(CHUNK, total - cb_);
        #pragma unroll 4
        for (int k = 0; k < n; ++k) {
            const float4 A  = s_a[k];   // px, py, qa, qb
            const float4 Bv = s_b[k];   // qc, lb, cr, cg
            const float cbv = s_c[k];
            const float dy   = fY - A.y;
            const float qbdy = A.w * dy;
            const float bse  = Bv.x * dy * dy + Bv.y;        // qc*dy^2 + lb
            const float dx0  = fX - A.x;
#define PX_BLEND(i, T, Rr, Gg, Bb)                                            \
            {                                                                 \
                const float dx = dx0 + (float)i;                              \
                const float q = (A.z * dx + qbdy) * dx + bse;                 \
                const float e = exp2f(q);                                     \
                const float alpha = __builtin_amdgcn_fmed3f(e, 0.01f, 0.99f); \
                const float w_ = alpha * T;                                   \
                Rr += w_ * Bv.z; Gg += w_ * Bv.w; Bb += w_ * cbv;             \
                T -= w_;                                                      \
            }
            PX_BLEND(0, T0, R0, G0, B0)
            PX_BLEND(1, T1, R1, G1, B1)
#undef PX_BLEND
        }
    }

    const int o0 = (X0 * W_IMG + Y) * 3;
    out[o0 + 0] = R0; out[o0 + 1] = G0; out[o0 + 2] = B0;
    out[o0 + W_IMG * 3 + 0] = R1; out[o0 + W_IMG * 3 + 1] = G1; out[o0 + W_IMG * 3 + 2] = B1;
}

extern "C" void kernel_launch(void* const* d_in, const int* in_sizes, int n_in,
                              void* d_out, int out_size, void* d_ws, size_t ws_size,
                              hipStream_t stream) {
    const float* pos2d   = (const float*)d_in[0];
    const float* cov2d   = (const float*)d_in[1];
    const float* opacity = (const float*)d_in[2];
    const float* color   = (const float*)d_in[3];
    float* out = (float*)d_out;

    char* ws = (char*)d_ws;
    float4* a4 = (float4*)(ws);
    float4* b4 = (float4*)(ws + 65536);
    float*  c1 = (float*)(ws + 131072);
    unsigned long long* tm = (unsigned long long*)(ws + 147456);

    gs_preprocess<<<N_G / 8, 256, 0, stream>>>(pos2d, cov2d, opacity, color,
                                               a4, b4, c1, tm);
    gs_render<<<NTILES * 8, 256, 0, stream>>>(a4, b4, c1, tm, out);
}